// Round 14
// baseline (21.891 us; speedup 1.0000x reference)
//
#include <hip/hip_runtime.h>

// ROI max-pooling, TF-style integer binning (matches the JAX reference).
// Round 14: 2-level max pyramid to cut the gathered line count ~2x.
//  pass 1 (build_pyr): P[b][h2][w][c]  = max(F[2h2][w], F[2h2+1][w])
//                      Q[b][h2][w2][c] = max(P[h2][2w2], P[h2][2w2+1])
//  pass 2: each bin window = interior quads (Q) + <=2 edge cols per
//  pair-row (P) + <=2 edge rows (F). Max is idempotent/associative ->
//  decomposition exact for any [lo,hi) window incl. degenerate bins.
// Rationale: plateau 15.7-17.7us invariant to occupancy/balance/MLP ->
// per-CU line-fill (MSHR x latency) bound; only fewer lines helps.
// Wrapper = R10 (1568 blocks x 256, permuted 2 bins/wave, %8 pinning,
// NT output stores). Fallback to direct kernel if ws too small.

#define OUT_H 7
#define OUT_W 7
#define NBIN (OUT_H * OUT_W)   // 49
#define NB 4
#define NR 64
#define NH 56
#define NW 56
#define NC 256
#define C4 (NC / 4)            // 64 float4 groups per pixel
#define NH2 (NH / 2)           // 28 row-pairs
#define NW2 (NW / 2)           // 28 col-pairs

#define NBLOCKS 1568           // fully resident; 196 per XCD
#define BLKS_PER_XCD_SLOT 196
#define BINS_PER_IMG (NR * NBIN)   // 3136
#define PERM_MUL 597           // coprime to 3136

#define P_ELEMS ((size_t)NB * NH2 * NW * NC)    // 1,605,632 floats (6.4 MB)
#define Q_ELEMS ((size_t)NB * NH2 * NW2 * NC)   //   802,816 floats (3.2 MB)
#define WS_NEEDED (((size_t)P_ELEMS + Q_ELEMS) * sizeof(float))

typedef float v4f __attribute__((ext_vector_type(4)));

__device__ __forceinline__ v4f vmax4(v4f a, v4f b) {
    v4f r;
    r.x = fmaxf(a.x, b.x);
    r.y = fmaxf(a.y, b.y);
    r.z = fmaxf(a.z, b.z);
    r.w = fmaxf(a.w, b.w);
    return r;
}

// ---------------- pass 1: pyramid build ----------------
// grid 448 x 64thr: block -> (b, h2, 14-col chunk); lane = c4 group.
__global__ __launch_bounds__(64) void build_pyr(
    const float* __restrict__ fmap, float* __restrict__ P, float* __restrict__ Q)
{
    const int blk   = blockIdx.x;        // [0,448)
    const int b     = blk / 112;
    const int rem   = blk - b * 112;
    const int h2    = rem >> 2;          // [0,28)
    const int chunk = rem & 3;           // [0,4) -> cols [14*chunk, +14)
    const int c0    = chunk * 14;
    const int lane  = threadIdx.x;

    const v4f* F0 = (const v4f*)(fmap + ((size_t)(b * NH + 2 * h2) * NW) * NC) + lane;
    const v4f* F1 = F0 + (size_t)NW * C4;
    v4f* Pp = (v4f*)(P + ((size_t)(b * NH2 + h2) * NW) * NC) + lane;
    v4f* Qp = (v4f*)(Q + ((size_t)(b * NH2 + h2) * NW2) * NC) + lane;

    v4f pprev;
#pragma unroll
    for (int k = 0; k < 14; ++k) {
        const int w = c0 + k;
        v4f p = vmax4(F0[(size_t)w * C4], F1[(size_t)w * C4]);
        Pp[(size_t)w * C4] = p;
        if (k & 1) Qp[(size_t)(w >> 1) * C4] = vmax4(pprev, p);
        pprev = p;
    }
}

// ---------------- window evaluators ----------------
// Direct (fallback): R5's compact 2x2 / 4-acc loop.
__device__ __forceinline__ v4f pool_window_direct(
    const v4f* __restrict__ base, int rlo, int rhi, int clo, int chi)
{
    const v4f ninf = (v4f){-INFINITY, -INFINITY, -INFINITY, -INFINITY};
    v4f acc0 = ninf, acc1 = ninf, acc2 = ninf, acc3 = ninf;
    int h = rlo;
    for (; h + 1 < rhi; h += 2) {
        const v4f* r0p = base + (size_t)(h * NW) * C4;
        const v4f* r1p = r0p + (size_t)NW * C4;
        int w = clo;
        for (; w + 1 < chi; w += 2) {
            acc0 = vmax4(acc0, r0p[(size_t)w * C4]);
            acc1 = vmax4(acc1, r0p[(size_t)(w + 1) * C4]);
            acc2 = vmax4(acc2, r1p[(size_t)w * C4]);
            acc3 = vmax4(acc3, r1p[(size_t)(w + 1) * C4]);
        }
        if (w < chi) {
            acc0 = vmax4(acc0, r0p[(size_t)w * C4]);
            acc2 = vmax4(acc2, r1p[(size_t)w * C4]);
        }
    }
    if (h < rhi) {
        const v4f* r0p = base + (size_t)(h * NW) * C4;
        int w = clo;
        for (; w + 1 < chi; w += 2) {
            acc0 = vmax4(acc0, r0p[(size_t)w * C4]);
            acc1 = vmax4(acc1, r0p[(size_t)(w + 1) * C4]);
        }
        if (w < chi) acc0 = vmax4(acc0, r0p[(size_t)w * C4]);
    }
    return vmax4(vmax4(acc0, acc1), vmax4(acc2, acc3));
}

// Pyramid: quads + P-edge-cols + F-edge-rows.
__device__ __forceinline__ v4f pool_window_pyr(
    const v4f* __restrict__ Fb, const v4f* __restrict__ Pb,
    const v4f* __restrict__ Qb, int rlo, int rhi, int clo, int chi)
{
    const v4f ninf = (v4f){-INFINITY, -INFINITY, -INFINITY, -INFINITY};
    if (rhi <= rlo || chi <= clo) return ninf;

    const int p_lo = (rlo + 1) >> 1, p_hi = rhi >> 1;   // full row-pairs
    const int er0  = (rlo & 1) ? rlo : -1;              // top edge row
    const int er1  = (rhi & 1) ? (rhi - 1) : -1;        // bottom edge row
    const int q_lo = (clo + 1) >> 1, q_hi = chi >> 1;   // full col-pairs
    const int ec0  = (clo & 1) ? clo : -1;              // left edge col
    const int ec1  = (chi & 1) ? (chi - 1) : -1;        // right edge col

    v4f a0 = ninf, a1 = ninf;

    for (int p = p_lo; p < p_hi; ++p) {
        const v4f* Qrow = Qb + (size_t)(p * NW2) * C4;
        const v4f* Prow = Pb + (size_t)(p * NW) * C4;
        int q = q_lo;
        for (; q + 1 < q_hi; q += 2) {
            a0 = vmax4(a0, Qrow[(size_t)q * C4]);
            a1 = vmax4(a1, Qrow[(size_t)(q + 1) * C4]);
        }
        if (q < q_hi) a0 = vmax4(a0, Qrow[(size_t)q * C4]);
        if (ec0 >= 0) a0 = vmax4(a0, Prow[(size_t)ec0 * C4]);
        if (ec1 >= 0) a1 = vmax4(a1, Prow[(size_t)ec1 * C4]);
    }
#pragma unroll
    for (int e = 0; e < 2; ++e) {
        const int er = e ? er1 : er0;
        if (er < 0) continue;
        const v4f* Frow = Fb + (size_t)(er * NW) * C4;
        int w = clo;
        for (; w + 1 < chi; w += 2) {
            a0 = vmax4(a0, Frow[(size_t)w * C4]);
            a1 = vmax4(a1, Frow[(size_t)(w + 1) * C4]);
        }
        if (w < chi) a0 = vmax4(a0, Frow[(size_t)w * C4]);
    }
    return vmax4(a0, a1);
}

// ---------------- pass 2: main kernel ----------------
template <bool USE_PYR>
__global__ __launch_bounds__(256, 8) void roi_pool_kernel(
    const float* __restrict__ fmap,   // [B,H,W,C]
    const float* __restrict__ rois,   // [B,R,4]
    float* __restrict__ out,          // [B,R,7,7,C]
    const float* __restrict__ P,      // [B,28,56,C]
    const float* __restrict__ Q)      // [B,28,28,C]
{
    const int blk  = blockIdx.x;
    const int xcd  = blk & 7;          // image b -> XCD pair {2b, 2b+1}
    const int b    = xcd >> 1;
    const int wid  = threadIdx.x >> 6;
    const int lane = threadIdx.x & 63;

    const int ibl = ((xcd & 1) * BLKS_PER_XCD_SLOT) + (blk >> 3); // [0,392)
    const int iw  = ibl * 4 + wid;                               // [0,1568)

    const v4f* Fb = (const v4f*)(fmap + (size_t)b * NH * NW * NC) + lane;
    const v4f* Pb = (const v4f*)(P + (size_t)b * NH2 * NW * NC) + lane;
    const v4f* Qb = (const v4f*)(Q + (size_t)b * NH2 * NW2 * NC) + lane;
    const float* roib = rois + (size_t)b * NR * 4;

#pragma unroll
    for (int t = 0; t < 2; ++t) {
        const int j    = 2 * iw + t;                       // [0, 3136)
        const int gbin = (j * PERM_MUL) % BINS_PER_IMG;    // permuted bin id
        const int r    = gbin / NBIN;
        const int bin  = gbin - r * NBIN;
        const int oi   = bin / OUT_W;
        const int oj   = bin - oi * OUT_W;

        const float* roi = roib + (size_t)r * 4;
        const float r0 = roi[0], r1 = roi[1], r2 = roi[2], r3 = roi[3];
        const int h0 = (int)((float)NH * r0);
        const int w0 = (int)((float)NW * r1);
        const int h1 = (int)((float)NH * r2);
        const int w1 = (int)((float)NW * r3);

        const int hstep = (int)((float)(h1 - h0) / (float)OUT_H);
        const int wstep = (int)((float)(w1 - w0) / (float)OUT_W);

        int rlo, rhi, clo, chi;
        if (hstep >= 1) {
            rlo = h0 + oi * hstep;
            rhi = (oi < OUT_H - 1) ? (rlo + hstep) : h1;
        } else {
            rlo = (oi == OUT_H - 1) ? h0 : 0;
            rhi = (oi == OUT_H - 1) ? h1 : 0;
        }
        if (wstep >= 1) {
            clo = w0 + oj * wstep;
            chi = (oj < OUT_W - 1) ? (clo + wstep) : w1;
        } else {
            clo = (oj == OUT_W - 1) ? w0 : 0;
            chi = (oj == OUT_W - 1) ? w1 : 0;
        }

        v4f m;
        if (USE_PYR)
            m = pool_window_pyr(Fb, Pb, Qb, rlo, rhi, clo, chi);
        else
            m = pool_window_direct(Fb, rlo, rhi, clo, chi);

        const size_t obase = ((size_t)((b * NR + r) * NBIN + bin)) * NC;
        v4f* o = (v4f*)(out + obase);
        __builtin_nontemporal_store(m, o + lane);
    }
}

extern "C" void kernel_launch(void* const* d_in, const int* in_sizes, int n_in,
                              void* d_out, int out_size, void* d_ws, size_t ws_size,
                              hipStream_t stream) {
    const float* fmap = (const float*)d_in[0];
    const float* rois = (const float*)d_in[1];
    float* out = (float*)d_out;

    if (ws_size >= WS_NEEDED) {
        float* P = (float*)d_ws;
        float* Q = P + P_ELEMS;
        build_pyr<<<NB * NH2 * 4, 64, 0, stream>>>(fmap, P, Q);
        roi_pool_kernel<true><<<NBLOCKS, 256, 0, stream>>>(fmap, rois, out, P, Q);
    } else {
        roi_pool_kernel<false><<<NBLOCKS, 256, 0, stream>>>(fmap, rois, out,
                                                            nullptr, nullptr);
    }
}